// Round 8
// baseline (98.560 us; speedup 1.0000x reference)
//
#include <hip/hip_runtime.h>
#include <math.h>

#define POOLED      7
#define OUTPUT_DIM  21
#define GROUP       7
#define CHANNELS    (OUTPUT_DIM * GROUP * GROUP)   // 1029
#define FH          64
#define FW          64
#define PLANE       (FH * FW)                      // 4096 floats, 16 KB
#define NUM_ROIS    1024
#define SCALE       0.0625f
#define NBLK        256                            // persistent blocks, 1/CU

// Opaque VGPR pin: blocks FMA contraction (hipcc -ffp-contract=fast ignores
// `#pragma clang fp contract(off)`). CORRECTNESS-CRITICAL: the golden's
// boundary chain is f32, separately rounded, with bin = roi * RN(1/7)
// (reciprocal multiply) — verified round 10, absmax 3.9e-3. Do not change.
__device__ __forceinline__ float freeze(float x) {
    __asm__ volatile("" : "+v"(x));
    return x;
}

// ---- frozen boundary chain, value form (ops identical to r10-verified) ----
struct RoiGeom { int b; float start_h, start_w, bin_h, bin_w; };

__device__ __forceinline__ RoiGeom roi_geom_v(float r0, float r1, float r2,
                                              float r3, float r4) {
    RoiGeom g;
    g.b = (int)r0;
    float start_w = rintf(r1) * SCALE;            // np.round = half-even
    float start_h = rintf(r2) * SCALE;
    float end_w   = rintf(r3 + 1.0f) * SCALE;
    float end_h   = rintf(r4 + 1.0f) * SCALE;
    float roi_w = fmaxf(end_w - start_w, 0.1f);
    float roi_h = fmaxf(end_h - start_h, 0.1f);
    const float inv7 = 1.0f / 7.0f;               // RN(1/7)
    g.bin_h = freeze(roi_h * inv7);               // reciprocal multiply
    g.bin_w = freeze(roi_w * inv7);
    g.start_h = start_h;
    g.start_w = start_w;
    return g;
}

__device__ __forceinline__ void bin_bounds(const RoiGeom& g, int ph, int pw,
                                           int& hs, int& he, int& ws, int& we) {
    float mh0 = freeze((float)ph * g.bin_h);      // separate mul, then add
    float mh1 = freeze((float)(ph + 1) * g.bin_h);
    float mw0 = freeze((float)pw * g.bin_w);
    float mw1 = freeze((float)(pw + 1) * g.bin_w);

    float hs_f = floorf(mh0 + g.start_h);
    float he_f = ceilf (mh1 + g.start_h);
    float ws_f = floorf(mw0 + g.start_w);
    float we_f = ceilf (mw1 + g.start_w);

    hs = (int)fminf(fmaxf(hs_f, 0.0f), (float)FH);
    he = (int)fminf(fmaxf(he_f, 0.0f), (float)FH);
    ws = (int)fminf(fmaxf(ws_f, 0.0f), (float)FW);
    we = (int)fminf(fmaxf(we_f, 0.0f), (float)FW);
}

// Region sum — IDENTICAL op order to the R1-verified kernel (absmax 3.9e-3).
__device__ __forceinline__ float region_avg(const float* __restrict__ plane,
                                            int hs, int he, int ws, int we) {
    float s = 0.0f;
    for (int h = hs; h < he; ++h) {
        const float* row = plane + h * FW;
        for (int w = ws; w < we; ++w) s += row[w];
    }
    int area = (he - hs) * (we - ws);
    return (area <= 0) ? 0.0f : s / (float)area;
}

// STATIC DOUBLE-BUFFERED PERSISTENT PIPELINE (round 19). R7's pipeline was
// neutral (98.3) because the buffers were ONE __shared__ object indexed at
// RUNTIME (buf[cur] / buf[cur^1]): the compiler cannot prove the in-flight
// global_load_lds writes don't alias the compute buffer's ds_reads, so it
// conservatively drains vmcnt before the region sums -> R1's serial
// stage->compute schedule, unchanged. (Same failure class as guide rules
// #18/#20: runtime indexing defeats scheduling/alias analysis.)
// Fix: two SEPARATE named __shared__ arrays + hand-unrolled 5-phase
// sequence; every stage destination and compute source is a distinct
// compile-time object. Per phase: STAGE4(other, next-channel) -> compute
// current channel from THIS buffer (no barrier, no forced drain between)
// -> __syncthreads() (its vmcnt(0) drain IS the "next buffer ready"
// handshake). 256 blocks (1/CU), 1024 thr, block owns channels
// bid, bid+256, ... (blocks 0..4 take a 5th).
__global__ __launch_bounds__(1024)
void psroi_pipe2(const float* __restrict__ feat,
                 const float* __restrict__ rois,
                 float* __restrict__ ws) {
    const int bid = blockIdx.x;           // 0..255
    const int t   = threadIdx.x;          // 0..1023 == ROI index

    __shared__ float bufA[4 * PLANE];     // 64 KB — named, statically distinct
    __shared__ float bufB[4 * PLANE];     // 64 KB

    // ROI load + geometry ONCE (registers; overlaps first staging).
    const float* r = rois + (size_t)t * 5;
    float r0 = r[0], r1 = r[1], r2 = r[2], r3 = r[3], r4 = r[4];

#if defined(__has_builtin) && __has_builtin(__builtin_amdgcn_global_load_lds)
    typedef const void __attribute__((address_space(1)))* gas_t;
    typedef void __attribute__((address_space(3)))*       las_t;
#define STAGE4(dst, ch)                                                         \
    do {                                                                        \
        _Pragma("unroll")                                                       \
        for (int p_ = 0; p_ < 4; ++p_) {                                        \
            const float* s_ = feat + ((size_t)p_ * CHANNELS + (ch)) * PLANE     \
                            + 4 * (size_t)t;                                    \
            __builtin_amdgcn_global_load_lds((gas_t)s_,                         \
                                             (las_t)((dst) + p_ * PLANE + 4 * t),\
                                             16, 0, 0);                         \
        }                                                                       \
    } while (0)
#else
#define STAGE4(dst, ch)                                                         \
    do {                                                                        \
        _Pragma("unroll")                                                       \
        for (int p_ = 0; p_ < 4; ++p_) {                                        \
            const float4* s4_ = reinterpret_cast<const float4*>(                \
                feat + ((size_t)p_ * CHANNELS + (ch)) * PLANE);                 \
            reinterpret_cast<float4*>((dst) + p_ * PLANE)[t] = s4_[t];          \
        }                                                                       \
    } while (0)
#endif

    // Compute channel ch from a statically-named buffer.
#define COMPUTE(src, ch)                                                        \
    do {                                                                        \
        const int pw_ = (ch) % 7;                                               \
        const int ph_ = ((ch) / 7) % 7;                                         \
        int hs_, he_, ws_, we_;                                                 \
        bin_bounds(g, ph_, pw_, hs_, he_, ws_, we_);                            \
        float v_ = region_avg((src) + g.b * PLANE, hs_, he_, ws_, we_);         \
        ws[(size_t)(ch) * NUM_ROIS + t] = v_;                                   \
    } while (0)

    const int c0 = bid;
    const int c1 = bid + NBLK;            // < 1029 always (max 255+256=511)
    const int c2 = bid + 2 * NBLK;        // < 1029 always (max 767)
    const int c3 = bid + 3 * NBLK;        // < 1029 always (max 1023)
    const int c4 = bid + 4 * NBLK;        // valid only for bid < 5

    STAGE4(bufA, c0);
    const RoiGeom g = roi_geom_v(r0, r1, r2, r3, r4);
    __syncthreads();                      // bufA(c0) ready

    STAGE4(bufB, c1);                     // flies under compute of c0
    COMPUTE(bufA, c0);
    __syncthreads();                      // bufB(c1) ready; bufA free

    STAGE4(bufA, c2);
    COMPUTE(bufB, c1);
    __syncthreads();                      // bufA(c2) ready; bufB free

    STAGE4(bufB, c3);
    COMPUTE(bufA, c2);
    __syncthreads();                      // bufB(c3) ready; bufA free

    if (c4 < CHANNELS) STAGE4(bufA, c4);
    COMPUTE(bufB, c3);
    if (c4 < CHANNELS) {
        __syncthreads();                  // bufA(c4) ready
        COMPUTE(bufA, c4);
    }
#undef COMPUTE
#undef STAGE4
}

// ws[1029][1024] -> out[1024][1029]. 32x32 tiles, 256 threads, 33-pad LDS
// (conflict-free column reads). R1-verified byte-for-byte.
__global__ __launch_bounds__(256)
void transpose_cn(const float* __restrict__ ws, float* __restrict__ out) {
    __shared__ float tile[32][33];
    const int c0 = blockIdx.y * 32;
    const int n0 = blockIdx.x * 32;
    const int tx = threadIdx.x & 31;
    const int ty = threadIdx.x >> 5;              // 0..7

#pragma unroll
    for (int i = 0; i < 32; i += 8) {
        const int cc = c0 + ty + i;
        if (cc < CHANNELS)
            tile[ty + i][tx] = ws[(size_t)cc * NUM_ROIS + (n0 + tx)];
    }
    __syncthreads();
#pragma unroll
    for (int i = 0; i < 32; i += 8) {
        const int nn = n0 + ty + i;
        const int cc = c0 + tx;
        if (cc < CHANNELS)
            out[(size_t)nn * CHANNELS + cc] = tile[tx][ty + i];
    }
}

// ---------- fallback path (R1-verified, no workspace) ----------
__global__ __launch_bounds__(1024)
void psroi_lds_direct(const float* __restrict__ feat,
                      const float* __restrict__ rois,
                      float* __restrict__ dst) {
    const int c  = blockIdx.x;
    const int pw = c % 7;
    const int ph = (c / 7) % 7;
    const int t  = threadIdx.x;

    __shared__ float pl[4 * PLANE];

    const float* r = rois + (size_t)t * 5;
    float r0 = r[0], r1 = r[1], r2 = r[2], r3 = r[3], r4 = r[4];

#pragma unroll
    for (int bb = 0; bb < 4; ++bb) {
        const float4* src = reinterpret_cast<const float4*>(
            feat + ((size_t)bb * CHANNELS + c) * PLANE);
        reinterpret_cast<float4*>(pl + bb * PLANE)[t] = src[t];
    }

    RoiGeom g = roi_geom_v(r0, r1, r2, r3, r4);
    int hs, he, wss, wee;
    bin_bounds(g, ph, pw, hs, he, wss, wee);

    __syncthreads();

    float v = region_avg(pl + g.b * PLANE, hs, he, wss, wee);
    dst[(size_t)t * CHANNELS + c] = v;
}

extern "C" void kernel_launch(void* const* d_in, const int* in_sizes, int n_in,
                              void* d_out, int out_size, void* d_ws, size_t ws_size,
                              hipStream_t stream) {
    const float* feat = (const float*)d_in[0];
    const float* rois = (const float*)d_in[1];
    float* out = (float*)d_out;

    const size_t need = sizeof(float) * (size_t)CHANNELS * NUM_ROIS;
    if (d_ws != nullptr && ws_size >= need) {
        float* wsp = (float*)d_ws;
        psroi_pipe2<<<NBLK, 1024, 0, stream>>>(feat, rois, wsp);
        transpose_cn<<<dim3(NUM_ROIS / 32, (CHANNELS + 31) / 32), 256, 0, stream>>>(wsp, out);
    } else {
        psroi_lds_direct<<<CHANNELS, 1024, 0, stream>>>(feat, rois, out);
    }
}

// Round 9
// 98.056 us; speedup vs baseline: 1.0051x; 1.0051x over previous
//
#include <hip/hip_runtime.h>
#include <math.h>

#define POOLED      7
#define OUTPUT_DIM  21
#define GROUP       7
#define CHANNELS    (OUTPUT_DIM * GROUP * GROUP)   // 1029
#define FH          64
#define FW          64
#define PLANE       (FH * FW)                      // 4096 floats, 16 KB
#define NUM_ROIS    1024
#define SCALE       0.0625f

// Opaque VGPR pin: blocks FMA contraction (hipcc -ffp-contract=fast ignores
// `#pragma clang fp contract(off)`). CORRECTNESS-CRITICAL: the golden's
// boundary chain is f32, separately rounded, with bin = roi * RN(1/7)
// (reciprocal multiply) — verified round 10, absmax 3.9e-3. Do not change.
__device__ __forceinline__ float freeze(float x) {
    __asm__ volatile("" : "+v"(x));
    return x;
}

// ROI-dependent (channel-independent) prefix of the frozen chain.
// Ops are bit-identical to the verified chain.
struct RoiGeom { int b; float start_h, start_w, bin_h, bin_w; };

__device__ __forceinline__ RoiGeom roi_geom(const float* __restrict__ rois, int t) {
    const float* r = rois + t * 5;
    RoiGeom g;
    g.b = (int)r[0];
    float start_w = rintf(r[1]) * SCALE;          // np.round = half-even
    float start_h = rintf(r[2]) * SCALE;
    float end_w   = rintf(r[3] + 1.0f) * SCALE;
    float end_h   = rintf(r[4] + 1.0f) * SCALE;
    float roi_w = fmaxf(end_w - start_w, 0.1f);
    float roi_h = fmaxf(end_h - start_h, 0.1f);
    const float inv7 = 1.0f / 7.0f;               // RN(1/7)
    g.bin_h = freeze(roi_h * inv7);               // reciprocal multiply
    g.bin_w = freeze(roi_w * inv7);
    g.start_h = start_h;
    g.start_w = start_w;
    return g;
}

// ph/pw-dependent tail of the frozen chain + LDS region sum.
__device__ __forceinline__ float bin_value(const RoiGeom& g, int ph, int pw,
                                           const float* __restrict__ pl) {
    float mh0 = freeze((float)ph * g.bin_h);      // separate mul, then add
    float mh1 = freeze((float)(ph + 1) * g.bin_h);
    float mw0 = freeze((float)pw * g.bin_w);
    float mw1 = freeze((float)(pw + 1) * g.bin_w);

    float hs_f = floorf(mh0 + g.start_h);
    float he_f = ceilf (mh1 + g.start_h);
    float ws_f = floorf(mw0 + g.start_w);
    float we_f = ceilf (mw1 + g.start_w);

    int hs = (int)fminf(fmaxf(hs_f, 0.0f), (float)FH);
    int he = (int)fminf(fmaxf(he_f, 0.0f), (float)FH);
    int ws = (int)fminf(fmaxf(ws_f, 0.0f), (float)FW);
    int we = (int)fminf(fmaxf(we_f, 0.0f), (float)FW);

    const float* base = pl + g.b * PLANE;
    float s = 0.0f;
    for (int h = hs; h < he; ++h) {
        const float* row = base + h * FW;
        for (int w = ws; w < we; ++w) s += row[w];
    }
    int area = (he - hs) * (we - ws);
    return (area <= 0) ? 0.0f : s / (float)area;
}

// BIN-MAJOR + LDS-STAGED (round-12 structure — the measured optimum, 96.78 us;
// round-20 = final revert to it). One block per channel c=(d*7+ph)*7+pw;
// block stages its exclusive working set (4 batch planes x 16 KB = 64 KB)
// into LDS with coalesced float4 loads -> HBM feature fetch is exactly-once
// and fully coalesced. 1024 threads (16 waves), 1 ROI/thread; 64 KB LDS =>
// 2 blocks/CU = 32 waves/CU. Cross-block overlap (block A computes while
// block B stages) is the pipeline — R3 (global_load_lds), R7 (runtime dbuf)
// and R8 (static dbuf) all measured neutral-to-worse (97.5/98.3/98.6), and
// R2 (grid.sync fusion, 297), R4 (grid split, 110), R5 (batch-phased, 103),
// R6 (LDS SAT, 140) all regressed. Do not re-attempt without new evidence.
//
// TO_WS=true: write ws[c*1024+n] (coalesced 4 KB row per block); the tiled
// transpose then emits out[n*1029+c]. Kills the 11x write amplification
// (47 MB -> 8.6 MB) + ~38 MB RMW fetch of the direct scatter store.
template<bool TO_WS>
__global__ __launch_bounds__(1024)
void psroi_lds(const float* __restrict__ feat,
               const float* __restrict__ rois,
               float* __restrict__ dst) {
    const int c  = blockIdx.x;            // 0..1028  (== d*49 + ph*7 + pw)
    const int pw = c % 7;
    const int ph = (c / 7) % 7;
    const int t  = threadIdx.x;           // 0..1023 == ROI index

    __shared__ float pl[4 * PLANE];       // 64 KB: 4 batch planes of channel c

    // ROI load + boundary chain first: independent of LDS, overlaps staging.
    const RoiGeom g = roi_geom(rois, t);

    // Stage 4 batch planes of channel c: 4x 16 KB, one float4 per thread per
    // batch, fully coalesced (1024 lanes x 16 B = one 16 KB plane per iter).
#pragma unroll
    for (int bb = 0; bb < 4; ++bb) {
        const float4* src = reinterpret_cast<const float4*>(
            feat + ((size_t)bb * CHANNELS + c) * PLANE);
        reinterpret_cast<float4*>(pl + bb * PLANE)[t] = src[t];
    }
    __syncthreads();

    float v = bin_value(g, ph, pw, pl);

    if (TO_WS) {
        dst[(size_t)c * NUM_ROIS + t] = v;        // coalesced, contiguous 4 KB
    } else {
        dst[(size_t)t * CHANNELS + c] = v;        // fallback scatter store
    }
}

// ws[1029][1024] -> out[1024][1029]. 32x32 tiles, 256 threads, 33-pad LDS
// (conflict-free column reads). Reads coalesced along n, writes coalesced
// along c. Traffic: 4.2 MB in + 4.2 MB out. R1-verified byte-for-byte.
__global__ __launch_bounds__(256)
void transpose_cn(const float* __restrict__ ws, float* __restrict__ out) {
    __shared__ float tile[32][33];
    const int c0 = blockIdx.y * 32;
    const int n0 = blockIdx.x * 32;
    const int tx = threadIdx.x & 31;
    const int ty = threadIdx.x >> 5;              // 0..7

#pragma unroll
    for (int i = 0; i < 32; i += 8) {
        const int cc = c0 + ty + i;
        if (cc < CHANNELS)
            tile[ty + i][tx] = ws[(size_t)cc * NUM_ROIS + (n0 + tx)];
    }
    __syncthreads();
#pragma unroll
    for (int i = 0; i < 32; i += 8) {
        const int nn = n0 + ty + i;
        const int cc = c0 + tx;
        if (cc < CHANNELS)
            out[(size_t)nn * CHANNELS + cc] = tile[tx][ty + i];
    }
}

extern "C" void kernel_launch(void* const* d_in, const int* in_sizes, int n_in,
                              void* d_out, int out_size, void* d_ws, size_t ws_size,
                              hipStream_t stream) {
    const float* feat = (const float*)d_in[0];
    const float* rois = (const float*)d_in[1];
    float* out = (float*)d_out;

    const size_t need = sizeof(float) * (size_t)CHANNELS * NUM_ROIS;
    if (d_ws != nullptr && ws_size >= need) {
        float* wsp = (float*)d_ws;
        psroi_lds<true><<<CHANNELS, 1024, 0, stream>>>(feat, rois, wsp);
        transpose_cn<<<dim3(NUM_ROIS / 32, (CHANNELS + 31) / 32), 256, 0, stream>>>(wsp, out);
    } else {
        psroi_lds<false><<<CHANNELS, 1024, 0, stream>>>(feat, rois, out);
    }
}